// Round 4
// baseline (824.428 us; speedup 1.0000x reference)
//
#include <hip/hip_runtime.h>
#include <cstdint>
#include <cstddef>

#define NEXP 4
#define CH   128      // c_
#define C1   256
#define C2   256
#define HWSZ 6400     // 80*80
#define NTOKS 204800  // 32*6400
#define BNE  1e-3f

using f32x4 = __attribute__((ext_vector_type(4))) float;
using f16x8 = __attribute__((ext_vector_type(8))) _Float16;
using f16x4 = __attribute__((ext_vector_type(4))) _Float16;
using s16x8 = __attribute__((ext_vector_type(8))) short;

static __device__ __forceinline__ unsigned short f2bf(float f) {
    union { float f; unsigned u; } v; v.f = f;
    unsigned r = v.u + 0x7fffu + ((v.u >> 16) & 1u);
    return (unsigned short)(r >> 16);
}
static __device__ __forceinline__ f32x4 zero4() {
    f32x4 z; z[0] = 0.f; z[1] = 0.f; z[2] = 0.f; z[3] = 0.f; return z;
}

// ---------------------------------------------------------------- k0: pack weights once (plain layouts, no swizzle)
// blocks [0,256): cen = bf16 ew[:,:,:,1,1]  (4*128*128)
// blocks [256,384): w1s = Dekker hi/lo f16 split of w1, layout [slice8][part2][o128][k32]
// blocks [384,512): w3p = bf16 w3, layout [slice4][o256][k32]
__global__ __launch_bounds__(256) void k0_pack(const float* __restrict__ ew,
                                               const float* __restrict__ w1,
                                               const float* __restrict__ w3,
                                               unsigned short* __restrict__ cen,
                                               _Float16* __restrict__ w1s,
                                               unsigned short* __restrict__ w3p) {
    int bid = blockIdx.x;
    int tid = threadIdx.x;
    if (bid < 256) {
        int idx = bid * 256 + tid;                       // (e*128+o)*128+c
        cen[idx] = f2bf(ew[(size_t)idx * 9 + 4]);
    } else if (bid < 384) {
        int lin = (bid - 256) * 256 + tid;               // 0..32767
        int o = lin >> 8, k = lin & 255;
        int s = k >> 5, kk = k & 31;
        float v = w1[o * C1 + k];
        _Float16 h = (_Float16)v;
        w1s[((s * 2 + 0) * 128 + o) * 32 + kk] = h;
        w1s[((s * 2 + 1) * 128 + o) * 32 + kk] = (_Float16)((v - (float)h) * 2048.0f);
    } else {
        int lin = (bid - 384) * 256 + tid;               // 0..32767
        int o = lin >> 7, k = lin & 127;
        int s = k >> 5, kk = k & 31;
        w3p[(s * 256 + o) * 32 + kk] = f2bf(w3[o * CH + k]);
    }
}

// ---------------------------------------------------------------- k1: conv1 (fp16x2-split MFMA) + BN + SiLU + router
// grid 3200 x 64 tokens. Software-pipelined: x prefetched one 32-K slice ahead into
// registers; B hi/lo planes double-buffered in k-major LDS (conflict-free, unpadded);
// ONE barrier per slice, nothing in the vmem queue at barrier time. A from L2 global.
__global__ __launch_bounds__(256, 4) void k1_conv1_router(
    const float* __restrict__ x, const _Float16* __restrict__ w1s,
    const float* __restrict__ bn1_g, const float* __restrict__ bn1_b,
    const float* __restrict__ bn1_m, const float* __restrict__ bn1_v,
    const float* __restrict__ rw, const float* __restrict__ rb,
    unsigned short* __restrict__ tokens, float* __restrict__ wd)
{
    const int tid  = threadIdx.x;
    const int lane = tid & 63;
    const int n15  = lane & 15;
    const int quad = lane >> 4;
    const int wv   = tid >> 6;

    const int nt0 = blockIdx.x * 64;
    const int b   = nt0 / HWSZ;
    const int hw0 = nt0 % HWSZ;

    // B planes: k-major [kgroup4][tok64][8 halves] per plane -> 4KB each, x2 (hi/lo), x2 buffers
    __shared__ union {
        struct { _Float16 Bh[2][2048]; _Float16 Bl[2][2048]; } s;       // 16 KB
        struct { float tokh[32 * 132]; float logit[128]; } e;           // 17.4 KB (32-token phase)
    } u;
    __shared__ float s1_l[128], t1_l[128];

    if (tid < 128) {
        float s = bn1_g[tid] / sqrtf(bn1_v[tid] + BNE);
        s1_l[tid] = s;
        t1_l[tid] = bn1_b[tid] - bn1_m[tid] * s;
    }

    f32x4 acc_m[2][4], acc_c[2][4];
    #pragma unroll
    for (int i = 0; i < 2; i++)
        #pragma unroll
        for (int j = 0; j < 4; j++) { acc_m[i][j] = zero4(); acc_c[i][j] = zero4(); }

    const int ti = tid & 63;      // token index this thread stages
    const int kg = tid >> 6;      // k-group 0..3 (8 channels each)

    float pf[2][8];               // prefetch regs, ping-pong by slice parity

    // prologue: load slice 0
    #pragma unroll
    for (int r = 0; r < 2; r++) {
        const float* xp = x + ((size_t)(b * C1 + 0 * 32 + kg * 8 + r * 4)) * HWSZ + hw0 + ti;
        #pragma unroll
        for (int j = 0; j < 4; j++) pf[0][r * 4 + j] = xp[(size_t)j * HWSZ];
    }

    #pragma unroll
    for (int S = 0; S < 8; S++) {
        const int pb = S & 1;
        // convert + store this slice's B (waits the prefetch loads)
        #pragma unroll
        for (int r = 0; r < 2; r++) {
            float v0 = pf[pb][r * 4 + 0], v1 = pf[pb][r * 4 + 1];
            float v2 = pf[pb][r * 4 + 2], v3 = pf[pb][r * 4 + 3];
            _Float16 h0 = (_Float16)v0, h1 = (_Float16)v1, h2 = (_Float16)v2, h3 = (_Float16)v3;
            f16x4 hv; hv[0] = h0; hv[1] = h1; hv[2] = h2; hv[3] = h3;
            f16x4 lv;
            lv[0] = (_Float16)((v0 - (float)h0) * 2048.0f);
            lv[1] = (_Float16)((v1 - (float)h1) * 2048.0f);
            lv[2] = (_Float16)((v2 - (float)h2) * 2048.0f);
            lv[3] = (_Float16)((v3 - (float)h3) * 2048.0f);
            *(f16x4*)&u.s.Bh[pb][(kg * 64 + ti) * 8 + r * 4] = hv;
            *(f16x4*)&u.s.Bl[pb][(kg * 64 + ti) * 8 + r * 4] = lv;
        }
        __syncthreads();
        // issue next slice's x loads AFTER the barrier (so the barrier never drains them);
        // they complete under this slice's MFMA phase and are consumed before the next barrier.
        if (S < 7) {
            #pragma unroll
            for (int r = 0; r < 2; r++) {
                const float* xp = x + ((size_t)(b * C1 + (S + 1) * 32 + kg * 8 + r * 4)) * HWSZ + hw0 + ti;
                #pragma unroll
                for (int j = 0; j < 4; j++) pf[pb ^ 1][r * 4 + j] = xp[(size_t)j * HWSZ];
            }
        }
        // A fragments from L2-resident w1s (plain layout)
        f16x8 a_h[2], a_l[2];
        #pragma unroll
        for (int mt = 0; mt < 2; mt++) {
            int row = (wv * 2 + mt) * 16 + n15;
            a_h[mt] = *(const f16x8*)&w1s[((S * 2 + 0) * 128 + row) * 32 + quad * 8];
            a_l[mt] = *(const f16x8*)&w1s[((S * 2 + 1) * 128 + row) * 32 + quad * 8];
        }
        #pragma unroll
        for (int nt = 0; nt < 4; nt++) {
            f16x8 b_h = *(const f16x8*)&u.s.Bh[pb][(quad * 64 + nt * 16 + n15) * 8];
            f16x8 b_l = *(const f16x8*)&u.s.Bl[pb][(quad * 64 + nt * 16 + n15) * 8];
            #pragma unroll
            for (int mt = 0; mt < 2; mt++) {
                acc_m[mt][nt] = __builtin_amdgcn_mfma_f32_16x16x32_f16(a_h[mt], b_h, acc_m[mt][nt], 0, 0, 0);
                acc_c[mt][nt] = __builtin_amdgcn_mfma_f32_16x16x32_f16(a_l[mt], b_h, acc_c[mt][nt], 0, 0, 0);
                acc_c[mt][nt] = __builtin_amdgcn_mfma_f32_16x16x32_f16(a_h[mt], b_l, acc_c[mt][nt], 0, 0, 0);
            }
        }
    }
    __syncthreads();

    // epilogue in two 32-token phases (halves the LDS scratch): BN + SiLU (f32) ->
    // router logits (exact f32 path) -> top-2 + bf16 token pack.
    #pragma unroll
    for (int h = 0; h < 2; h++) {
        if (h) __syncthreads();                 // protect tokh reuse across phases
        #pragma unroll
        for (int mt = 0; mt < 2; mt++)
            #pragma unroll
            for (int nt2 = 0; nt2 < 2; nt2++) {
                int nt = h * 2 + nt2;
                #pragma unroll
                for (int r = 0; r < 4; r++) {
                    int o  = (wv * 2 + mt) * 16 + quad * 4 + r;
                    int tk = nt2 * 16 + n15;
                    float y1 = acc_m[mt][nt][r] + acc_c[mt][nt][r] * (1.0f / 2048.0f);
                    float y  = y1 * s1_l[o] + t1_l[o];
                    u.e.tokh[tk * 132 + o] = y / (1.0f + __expf(-y));
                }
            }
        __syncthreads();

        if (tid < 128) {
            int tk = tid >> 2;                  // 0..31
            int e  = tid & 3;
            const float* trow = &u.e.tokh[tk * 132];
            const float* wrow = &rw[e * CH];
            float a0 = 0.f, a1 = 0.f, a2 = 0.f, a3 = 0.f;
            #pragma unroll 8
            for (int c = 0; c < CH; c += 4) {
                a0 = fmaf(trow[c + 0], wrow[c + 0], a0);
                a1 = fmaf(trow[c + 1], wrow[c + 1], a1);
                a2 = fmaf(trow[c + 2], wrow[c + 2], a2);
                a3 = fmaf(trow[c + 3], wrow[c + 3], a3);
            }
            u.e.logit[tk * 4 + e] = ((a0 + a1) + (a2 + a3)) + rb[e];
        }
        __syncthreads();

        if (tid < 32) {
            const float* lg = &u.e.logit[tid * 4];
            float l0 = lg[0], l1 = lg[1], l2 = lg[2], l3 = lg[3];
            int i1 = 0; float m1 = l0;
            if (l1 > m1) { m1 = l1; i1 = 1; }
            if (l2 > m1) { m1 = l2; i1 = 2; }
            if (l3 > m1) { m1 = l3; i1 = 3; }
            int i2 = -1; float m2 = -3.4e38f;
            if (i1 != 0 && l0 > m2) { m2 = l0; i2 = 0; }
            if (i1 != 1 && l1 > m2) { m2 = l1; i2 = 1; }
            if (i1 != 2 && l2 > m2) { m2 = l2; i2 = 2; }
            if (i1 != 3 && l3 > m2) { m2 = l3; i2 = 3; }
            float p2 = __expf(m2 - m1);
            float wa = 1.0f / (1.0f + p2);
            float wb = p2 * wa;
            float4 wout;
            wout.x = (i1 == 0) ? wa : ((i2 == 0) ? wb : 0.0f);
            wout.y = (i1 == 1) ? wa : ((i2 == 1) ? wb : 0.0f);
            wout.z = (i1 == 2) ? wa : ((i2 == 2) ? wb : 0.0f);
            wout.w = (i1 == 3) ? wa : ((i2 == 3) ? wb : 0.0f);
            *(float4*)&wd[(size_t)(nt0 + h * 32 + tid) * 4] = wout;
        }

        // tokens out as bf16 for these 32 rows
        #pragma unroll
        for (int rep = 0; rep < 4; rep++) {
            int lin = rep * 256 + tid;
            int n   = lin >> 5;                 // 0..31
            int c4  = (lin & 31) * 4;
            const float* tp = &u.e.tokh[n * 132 + c4];
            ushort4 pk;
            pk.x = f2bf(tp[0]); pk.y = f2bf(tp[1]); pk.z = f2bf(tp[2]); pk.w = f2bf(tp[3]);
            *(ushort4*)&tokens[(size_t)(nt0 + h * 32 + n) * CH + c4] = pk;
        }
    }
}

// ---------------------------------------------------------------- k2: 4 experts + BN + SiLU + weighted combine
// grid 3200 x 64 tokens; wave wv owns o-band [wv*32, +32) for all 64 tokens.
// ONE barrier total. cen A-fragments ping-ponged global(L2)->VGPR one step ahead.
__global__ __launch_bounds__(256, 4) void k2_experts(
    const unsigned short* __restrict__ tokens, const unsigned short* __restrict__ cen,
    const float* __restrict__ wd,
    const float* __restrict__ ebn_g, const float* __restrict__ ebn_b,
    const float* __restrict__ ebn_m, const float* __restrict__ ebn_v,
    unsigned short* __restrict__ moe)
{
    const int tid  = threadIdx.x;
    const int lane = tid & 63;
    const int wv   = tid >> 6;
    const int n15  = lane & 15;
    const int quad = lane >> 4;
    const int nt0  = blockIdx.x * 64;

    __shared__ unsigned short Bt[64 * 136];    // tokens [tok][c] pitch 136 (17.4 KB)
    __shared__ float wd_l[256];                // [tok][e]
    __shared__ float inv_l[512], sh_l[512];    // [e*128+o]

    #pragma unroll
    for (int rep = 0; rep < 4; rep++) {
        int lin = rep * 256 + tid;
        int n   = lin >> 4;
        int c8  = (lin & 15) * 8;
        *(uint4*)&Bt[n * 136 + c8] = *(const uint4*)&tokens[(size_t)(nt0 + n) * CH + c8];
    }
    wd_l[tid] = wd[(size_t)nt0 * 4 + tid];
    #pragma unroll
    for (int r = 0; r < 2; r++) {
        int idx = r * 256 + tid;
        float iv = ebn_g[idx] / sqrtf(ebn_v[idx] + BNE);
        inv_l[idx] = iv;
        sh_l[idx]  = ebn_b[idx] - ebn_m[idx] * iv;
    }

    f32x4 acc[2][4], oacc[2][4];
    #pragma unroll
    for (int i = 0; i < 2; i++)
        #pragma unroll
        for (int j = 0; j < 4; j++) { acc[i][j] = zero4(); oacc[i][j] = zero4(); }

    s16x8 ap[2][2];                            // A ping-pong: [parity][mt]
    #pragma unroll
    for (int mt = 0; mt < 2; mt++)
        ap[0][mt] = *(const s16x8*)&cen[((size_t)(0 * CH) + wv * 32 + mt * 16 + n15) * CH + 0 * 32 + quad * 8];

    __syncthreads();   // the only barrier

    #pragma unroll
    for (int ek = 0; ek < 16; ek++) {
        const int e   = ek >> 2;
        const int kk  = ek & 3;
        const int cur = ek & 1;
        if (ek < 15) {
            const int en = (ek + 1) >> 2, kn = (ek + 1) & 3;
            #pragma unroll
            for (int mt = 0; mt < 2; mt++)
                ap[cur ^ 1][mt] = *(const s16x8*)&cen[((size_t)(en * CH) + wv * 32 + mt * 16 + n15) * CH + kn * 32 + quad * 8];
        }
        s16x8 bb[4];
        #pragma unroll
        for (int nt = 0; nt < 4; nt++)
            bb[nt] = *(const s16x8*)&Bt[(nt * 16 + n15) * 136 + kk * 32 + quad * 8];
        #pragma unroll
        for (int mt = 0; mt < 2; mt++)
            #pragma unroll
            for (int nt = 0; nt < 4; nt++)
                acc[mt][nt] = __builtin_amdgcn_mfma_f32_16x16x32_bf16(ap[cur][mt], bb[nt], acc[mt][nt], 0, 0, 0);

        if (kk == 3) {
            #pragma unroll
            for (int mt = 0; mt < 2; mt++)
                #pragma unroll
                for (int nt = 0; nt < 4; nt++) {
                    float wde = wd_l[(nt * 16 + n15) * 4 + e];
                    #pragma unroll
                    for (int r = 0; r < 4; r++) {
                        int o = wv * 32 + mt * 16 + quad * 4 + r;
                        float y = acc[mt][nt][r] * inv_l[e * CH + o] + sh_l[e * CH + o];
                        oacc[mt][nt][r] += wde * (y / (1.0f + __expf(-y)));
                    }
                    acc[mt][nt] = zero4();
                }
        }
    }

    #pragma unroll
    for (int mt = 0; mt < 2; mt++)
        #pragma unroll
        for (int nt = 0; nt < 4; nt++) {
            int tk = nt * 16 + n15;
            int ob = wv * 32 + mt * 16 + quad * 4;
            ushort4 pk;
            pk.x = f2bf(oacc[mt][nt][0]); pk.y = f2bf(oacc[mt][nt][1]);
            pk.z = f2bf(oacc[mt][nt][2]); pk.w = f2bf(oacc[mt][nt][3]);
            *(ushort4*)&moe[(size_t)(nt0 + tk) * CH + ob] = pk;
        }
}

// ---------------------------------------------------------------- k3: conv3 + BN + SiLU + residual
// grid 3200 x 64 tokens. Whole B-tile staged once (1 barrier); w3p fragments
// global->VGPR per slice; coalesced epilogue via LDS f32 transpose.
__global__ __launch_bounds__(256, 3) void k3_conv3(
    const unsigned short* __restrict__ moe, const unsigned short* __restrict__ w3p,
    const float* __restrict__ bn3_g, const float* __restrict__ bn3_b,
    const float* __restrict__ bn3_m, const float* __restrict__ bn3_v,
    const float* __restrict__ x, float* __restrict__ out)
{
    const int tid  = threadIdx.x;
    const int lane = tid & 63;
    const int wv   = tid >> 6;
    const int n15  = lane & 15;
    const int quad = lane >> 4;
    const int nt0  = blockIdx.x * 64;
    const int b    = nt0 / HWSZ;
    const int hw0  = nt0 % HWSZ;

    __shared__ union {
        unsigned short B3[64 * 136];   // moe tile [tok][c] pitch 136 (17.4 KB)
        float scr[128 * 68];           // f32 transpose scratch [o_l][tok] pitch 68 (34.8 KB)
    } u;
    __shared__ float s3_l[256], t3_l[256];

    {
        float s = bn3_g[tid] / sqrtf(bn3_v[tid] + BNE);
        s3_l[tid] = s;
        t3_l[tid] = bn3_b[tid] - bn3_m[tid] * s;
    }

    // stage whole B: 64 rows x 256B, 32B per thread
    #pragma unroll
    for (int rep = 0; rep < 2; rep++) {
        int lin = rep * 256 + tid;
        int n   = lin >> 3;
        int c16 = (lin & 7) * 16;
        *(uint4*)&u.B3[n * 136 + c16]     = *(const uint4*)&moe[(size_t)(nt0 + n) * CH + c16];
        *(uint4*)&u.B3[n * 136 + c16 + 8] = *(const uint4*)&moe[(size_t)(nt0 + n) * CH + c16 + 8];
    }

    f32x4 acc[4][4];
    #pragma unroll
    for (int i = 0; i < 4; i++)
        #pragma unroll
        for (int j = 0; j < 4; j++) acc[i][j] = zero4();

    __syncthreads();

    for (int s = 0; s < 4; s++) {
        s16x8 af[4];
        #pragma unroll
        for (int mt = 0; mt < 4; mt++) {
            int row = (wv * 4 + mt) * 16 + n15;
            af[mt] = *(const s16x8*)&w3p[(s * 256 + row) * 32 + quad * 8];
        }
        s16x8 bf[4];
        #pragma unroll
        for (int nt = 0; nt < 4; nt++)
            bf[nt] = *(const s16x8*)&u.B3[(nt * 16 + n15) * 136 + s * 32 + quad * 8];
        #pragma unroll
        for (int mt = 0; mt < 4; mt++)
            #pragma unroll
            for (int nt = 0; nt < 4; nt++)
                acc[mt][nt] = __builtin_amdgcn_mfma_f32_16x16x32_bf16(af[mt], bf[nt], acc[mt][nt], 0, 0, 0);
    }

    // epilogue: BN + SiLU, transpose via LDS f32 scratch, coalesced float4 residual+store.
    #pragma unroll
    for (int h = 0; h < 2; h++) {
        __syncthreads();
        if ((wv >> 1) == h) {
            int wvl = wv & 1;
            #pragma unroll
            for (int mt = 0; mt < 4; mt++)
                #pragma unroll
                for (int nt = 0; nt < 4; nt++) {
                    int tk = nt * 16 + n15;
                    #pragma unroll
                    for (int r = 0; r < 4; r++) {
                        int o_l = wvl * 64 + mt * 16 + quad * 4 + r;
                        int o2  = h * 128 + o_l;
                        float y = acc[mt][nt][r] * s3_l[o2] + t3_l[o2];
                        u.scr[o_l * 68 + tk] = y / (1.0f + __expf(-y));
                    }
                }
        }
        __syncthreads();
        #pragma unroll
        for (int rep = 0; rep < 8; rep++) {
            int lin = rep * 256 + tid;
            int row = lin >> 4;                 // 0..127
            int t4  = (lin & 15) * 4;
            int o2  = h * 128 + row;
            size_t g = ((size_t)(b * C2 + o2)) * HWSZ + hw0 + t4;
            f32x4 v = *(const f32x4*)&u.scr[row * 68 + t4];
            const float4 xs = *(const float4*)&x[g];
            float4 w;
            w.x = v[0] + xs.x; w.y = v[1] + xs.y; w.z = v[2] + xs.z; w.w = v[3] + xs.w;
            *(float4*)&out[g] = w;
        }
    }
}

// ----------------------------------------------------------------
extern "C" void kernel_launch(void* const* d_in, const int* in_sizes, int n_in,
                              void* d_out, int out_size, void* d_ws, size_t ws_size,
                              hipStream_t stream) {
    const float* x     = (const float*)d_in[0];
    const float* w1    = (const float*)d_in[1];
    const float* bn1_g = (const float*)d_in[2];
    const float* bn1_b = (const float*)d_in[3];
    const float* bn1_m = (const float*)d_in[4];
    const float* bn1_v = (const float*)d_in[5];
    const float* rw    = (const float*)d_in[6];
    const float* rb    = (const float*)d_in[7];
    const float* ew    = (const float*)d_in[8];
    const float* ebn_g = (const float*)d_in[9];
    const float* ebn_b = (const float*)d_in[10];
    const float* ebn_m = (const float*)d_in[11];
    const float* ebn_v = (const float*)d_in[12];
    const float* w3    = (const float*)d_in[13];
    const float* bn3_g = (const float*)d_in[14];
    const float* bn3_b = (const float*)d_in[15];
    const float* bn3_m = (const float*)d_in[16];
    const float* bn3_v = (const float*)d_in[17];
    float* out = (float*)d_out;

    char* ws = (char*)d_ws;
    unsigned short* tokens = (unsigned short*)(ws);                // N*128 bf16
    unsigned short* moe    = (unsigned short*)(ws + 52428800);     // N*128 bf16
    float*          wdv    = (float*)(ws + 104857600);             // N*4 f32
    unsigned short* cen    = (unsigned short*)(ws + 108134400);    // 4*128*128 bf16 = 131072 B
    _Float16*       w1s    = (_Float16*)(ws + 108265472);          // 2*128*256 f16 = 131072 B
    unsigned short* w3p    = (unsigned short*)(ws + 108396544);    // 256*128 bf16 = 65536 B

    k0_pack<<<dim3(512), dim3(256), 0, stream>>>(ew, w1, w3, cen, w1s, w3p);
    k1_conv1_router<<<dim3(3200), dim3(256), 0, stream>>>(x, w1s, bn1_g, bn1_b, bn1_m, bn1_v,
                                                          rw, rb, tokens, wdv);
    k2_experts<<<dim3(3200), dim3(256), 0, stream>>>(tokens, cen, wdv,
                                                     ebn_g, ebn_b, ebn_m, ebn_v, moe);
    k3_conv3<<<dim3(3200), dim3(256), 0, stream>>>(moe, w3p, bn3_g, bn3_b, bn3_m, bn3_v, x, out);
    (void)in_sizes; (void)n_in; (void)out_size; (void)ws_size;
}

// Round 5
// 637.323 us; speedup vs baseline: 1.2936x; 1.2936x over previous
//
#include <hip/hip_runtime.h>
#include <cstdint>
#include <cstddef>

#define NEXP 4
#define CH   128      // c_
#define C1   256
#define C2   256
#define HWSZ 6400     // 80*80
#define NTOKS 204800  // 32*6400
#define BNE  1e-3f

using f32x4 = __attribute__((ext_vector_type(4))) float;
using f16x8 = __attribute__((ext_vector_type(8))) _Float16;
using f16x4 = __attribute__((ext_vector_type(4))) _Float16;
using s16x8 = __attribute__((ext_vector_type(8))) short;

static __device__ __forceinline__ unsigned short f2bf(float f) {
    union { float f; unsigned u; } v; v.f = f;
    unsigned r = v.u + 0x7fffu + ((v.u >> 16) & 1u);
    return (unsigned short)(r >> 16);
}
static __device__ __forceinline__ f32x4 zero4() {
    f32x4 z; z[0] = 0.f; z[1] = 0.f; z[2] = 0.f; z[3] = 0.f; return z;
}

// ---------------------------------------------------------------- k0: pack weights once (plain layouts)
// blocks [0,256): cen = bf16 ew[:,:,:,1,1]  (4*128*128)
// blocks [256,384): w1s = Dekker hi/lo f16 split of w1, layout [slice8][part2][o128][k32]
// blocks [384,512): w3p = bf16 w3, layout [slice4][o256][k32]
__global__ __launch_bounds__(256) void k0_pack(const float* __restrict__ ew,
                                               const float* __restrict__ w1,
                                               const float* __restrict__ w3,
                                               unsigned short* __restrict__ cen,
                                               _Float16* __restrict__ w1s,
                                               unsigned short* __restrict__ w3p) {
    int bid = blockIdx.x;
    int tid = threadIdx.x;
    if (bid < 256) {
        int idx = bid * 256 + tid;                       // (e*128+o)*128+c
        cen[idx] = f2bf(ew[(size_t)idx * 9 + 4]);
    } else if (bid < 384) {
        int lin = (bid - 256) * 256 + tid;               // 0..32767
        int o = lin >> 8, k = lin & 255;
        int s = k >> 5, kk = k & 31;
        float v = w1[o * C1 + k];
        _Float16 h = (_Float16)v;
        w1s[((s * 2 + 0) * 128 + o) * 32 + kk] = h;
        w1s[((s * 2 + 1) * 128 + o) * 32 + kk] = (_Float16)((v - (float)h) * 2048.0f);
    } else {
        int lin = (bid - 384) * 256 + tid;               // 0..32767
        int o = lin >> 7, k = lin & 127;
        int s = k >> 5, kk = k & 31;
        w3p[(s * 256 + o) * 32 + kk] = f2bf(w3[o * CH + k]);
    }
}

// ---------------------------------------------------------------- k1: conv1 (fp16x2-split MFMA) + BN + SiLU + router
// (frozen from R4) grid 3200 x 64 tokens. x prefetched one 32-K slice ahead into regs;
// B hi/lo planes double-buffered in k-major LDS; one barrier per slice; A from L2 global.
__global__ __launch_bounds__(256, 4) void k1_conv1_router(
    const float* __restrict__ x, const _Float16* __restrict__ w1s,
    const float* __restrict__ bn1_g, const float* __restrict__ bn1_b,
    const float* __restrict__ bn1_m, const float* __restrict__ bn1_v,
    const float* __restrict__ rw, const float* __restrict__ rb,
    unsigned short* __restrict__ tokens, float* __restrict__ wd)
{
    const int tid  = threadIdx.x;
    const int lane = tid & 63;
    const int n15  = lane & 15;
    const int quad = lane >> 4;
    const int wv   = tid >> 6;

    const int nt0 = blockIdx.x * 64;
    const int b   = nt0 / HWSZ;
    const int hw0 = nt0 % HWSZ;

    __shared__ union {
        struct { _Float16 Bh[2][2048]; _Float16 Bl[2][2048]; } s;       // 16 KB
        struct { float tokh[32 * 132]; float logit[128]; } e;           // 17.4 KB (32-token phase)
    } u;
    __shared__ float s1_l[128], t1_l[128];

    if (tid < 128) {
        float s = bn1_g[tid] / sqrtf(bn1_v[tid] + BNE);
        s1_l[tid] = s;
        t1_l[tid] = bn1_b[tid] - bn1_m[tid] * s;
    }

    f32x4 acc_m[2][4], acc_c[2][4];
    #pragma unroll
    for (int i = 0; i < 2; i++)
        #pragma unroll
        for (int j = 0; j < 4; j++) { acc_m[i][j] = zero4(); acc_c[i][j] = zero4(); }

    const int ti = tid & 63;      // token index this thread stages
    const int kg = tid >> 6;      // k-group 0..3 (8 channels each)

    float pf[2][8];               // prefetch regs, ping-pong by slice parity

    #pragma unroll
    for (int r = 0; r < 2; r++) {
        const float* xp = x + ((size_t)(b * C1 + kg * 8 + r * 4)) * HWSZ + hw0 + ti;
        #pragma unroll
        for (int j = 0; j < 4; j++) pf[0][r * 4 + j] = xp[(size_t)j * HWSZ];
    }

    #pragma unroll
    for (int S = 0; S < 8; S++) {
        const int pb = S & 1;
        #pragma unroll
        for (int r = 0; r < 2; r++) {
            float v0 = pf[pb][r * 4 + 0], v1 = pf[pb][r * 4 + 1];
            float v2 = pf[pb][r * 4 + 2], v3 = pf[pb][r * 4 + 3];
            _Float16 h0 = (_Float16)v0, h1 = (_Float16)v1, h2 = (_Float16)v2, h3 = (_Float16)v3;
            f16x4 hv; hv[0] = h0; hv[1] = h1; hv[2] = h2; hv[3] = h3;
            f16x4 lv;
            lv[0] = (_Float16)((v0 - (float)h0) * 2048.0f);
            lv[1] = (_Float16)((v1 - (float)h1) * 2048.0f);
            lv[2] = (_Float16)((v2 - (float)h2) * 2048.0f);
            lv[3] = (_Float16)((v3 - (float)h3) * 2048.0f);
            *(f16x4*)&u.s.Bh[pb][(kg * 64 + ti) * 8 + r * 4] = hv;
            *(f16x4*)&u.s.Bl[pb][(kg * 64 + ti) * 8 + r * 4] = lv;
        }
        __syncthreads();
        if (S < 7) {
            #pragma unroll
            for (int r = 0; r < 2; r++) {
                const float* xp = x + ((size_t)(b * C1 + (S + 1) * 32 + kg * 8 + r * 4)) * HWSZ + hw0 + ti;
                #pragma unroll
                for (int j = 0; j < 4; j++) pf[pb ^ 1][r * 4 + j] = xp[(size_t)j * HWSZ];
            }
        }
        f16x8 a_h[2], a_l[2];
        #pragma unroll
        for (int mt = 0; mt < 2; mt++) {
            int row = (wv * 2 + mt) * 16 + n15;
            a_h[mt] = *(const f16x8*)&w1s[((S * 2 + 0) * 128 + row) * 32 + quad * 8];
            a_l[mt] = *(const f16x8*)&w1s[((S * 2 + 1) * 128 + row) * 32 + quad * 8];
        }
        #pragma unroll
        for (int nt = 0; nt < 4; nt++) {
            f16x8 b_h = *(const f16x8*)&u.s.Bh[pb][(quad * 64 + nt * 16 + n15) * 8];
            f16x8 b_l = *(const f16x8*)&u.s.Bl[pb][(quad * 64 + nt * 16 + n15) * 8];
            #pragma unroll
            for (int mt = 0; mt < 2; mt++) {
                acc_m[mt][nt] = __builtin_amdgcn_mfma_f32_16x16x32_f16(a_h[mt], b_h, acc_m[mt][nt], 0, 0, 0);
                acc_c[mt][nt] = __builtin_amdgcn_mfma_f32_16x16x32_f16(a_l[mt], b_h, acc_c[mt][nt], 0, 0, 0);
                acc_c[mt][nt] = __builtin_amdgcn_mfma_f32_16x16x32_f16(a_h[mt], b_l, acc_c[mt][nt], 0, 0, 0);
            }
        }
    }
    __syncthreads();

    #pragma unroll
    for (int h = 0; h < 2; h++) {
        if (h) __syncthreads();
        #pragma unroll
        for (int mt = 0; mt < 2; mt++)
            #pragma unroll
            for (int nt2 = 0; nt2 < 2; nt2++) {
                int nt = h * 2 + nt2;
                #pragma unroll
                for (int r = 0; r < 4; r++) {
                    int o  = (wv * 2 + mt) * 16 + quad * 4 + r;
                    int tk = nt2 * 16 + n15;
                    float y1 = acc_m[mt][nt][r] + acc_c[mt][nt][r] * (1.0f / 2048.0f);
                    float y  = y1 * s1_l[o] + t1_l[o];
                    u.e.tokh[tk * 132 + o] = y / (1.0f + __expf(-y));
                }
            }
        __syncthreads();

        if (tid < 128) {
            int tk = tid >> 2;
            int e  = tid & 3;
            const float* trow = &u.e.tokh[tk * 132];
            const float* wrow = &rw[e * CH];
            float a0 = 0.f, a1 = 0.f, a2 = 0.f, a3 = 0.f;
            #pragma unroll 8
            for (int c = 0; c < CH; c += 4) {
                a0 = fmaf(trow[c + 0], wrow[c + 0], a0);
                a1 = fmaf(trow[c + 1], wrow[c + 1], a1);
                a2 = fmaf(trow[c + 2], wrow[c + 2], a2);
                a3 = fmaf(trow[c + 3], wrow[c + 3], a3);
            }
            u.e.logit[tk * 4 + e] = ((a0 + a1) + (a2 + a3)) + rb[e];
        }
        __syncthreads();

        if (tid < 32) {
            const float* lg = &u.e.logit[tid * 4];
            float l0 = lg[0], l1 = lg[1], l2 = lg[2], l3 = lg[3];
            int i1 = 0; float m1 = l0;
            if (l1 > m1) { m1 = l1; i1 = 1; }
            if (l2 > m1) { m1 = l2; i1 = 2; }
            if (l3 > m1) { m1 = l3; i1 = 3; }
            int i2 = -1; float m2 = -3.4e38f;
            if (i1 != 0 && l0 > m2) { m2 = l0; i2 = 0; }
            if (i1 != 1 && l1 > m2) { m2 = l1; i2 = 1; }
            if (i1 != 2 && l2 > m2) { m2 = l2; i2 = 2; }
            if (i1 != 3 && l3 > m2) { m2 = l3; i2 = 3; }
            float p2 = __expf(m2 - m1);
            float wa = 1.0f / (1.0f + p2);
            float wb = p2 * wa;
            float4 wout;
            wout.x = (i1 == 0) ? wa : ((i2 == 0) ? wb : 0.0f);
            wout.y = (i1 == 1) ? wa : ((i2 == 1) ? wb : 0.0f);
            wout.z = (i1 == 2) ? wa : ((i2 == 2) ? wb : 0.0f);
            wout.w = (i1 == 3) ? wa : ((i2 == 3) ? wb : 0.0f);
            *(float4*)&wd[(size_t)(nt0 + h * 32 + tid) * 4] = wout;
        }

        #pragma unroll
        for (int rep = 0; rep < 4; rep++) {
            int lin = rep * 256 + tid;
            int n   = lin >> 5;
            int c4  = (lin & 31) * 4;
            const float* tp = &u.e.tokh[n * 132 + c4];
            ushort4 pk;
            pk.x = f2bf(tp[0]); pk.y = f2bf(tp[1]); pk.z = f2bf(tp[2]); pk.w = f2bf(tp[3]);
            *(ushort4*)&tokens[(size_t)(nt0 + h * 32 + n) * CH + c4] = pk;
        }
    }
}

// ---------------------------------------------------------------- k2: 4 experts + BN + SiLU + weighted combine
// R1-proven structure (grid 1600 x 128 tok, quadrant waves, LDS-staged cen) with a NEW
// coalesced store epilogue: oacc -> bf16 LDS tile -> cooperative uint4 row stores.
// Kills the ~16x write amplification of the old per-lane 8B scattered moe stores.
__global__ __launch_bounds__(256, 2) void k2_experts(
    const unsigned short* __restrict__ tokens, const unsigned short* __restrict__ cen,
    const float* __restrict__ wd,
    const float* __restrict__ ebn_g, const float* __restrict__ ebn_b,
    const float* __restrict__ ebn_m, const float* __restrict__ ebn_v,
    unsigned short* __restrict__ moe)
{
    const int tid  = threadIdx.x;
    const int lane = tid & 63;
    const int wv   = tid >> 6;
    const int n15  = lane & 15;
    const int quad = lane >> 4;
    const int qm   = wv & 1;        // o-half
    const int qn   = wv >> 1;       // token-half
    const int nt0  = blockIdx.x * 128;

    __shared__ unsigned short Bt[128 * 136];   // tokens [tok][c] pitch 136; reused for moe-out
    __shared__ unsigned short Ac[128 * 136];   // one expert's center [o][c]
    __shared__ float wd_l[512];                // [tok][e]
    __shared__ float inv_l[512], sh_l[512];    // [e*128+o]

    #pragma unroll
    for (int rep = 0; rep < 8; rep++) {
        int lin = rep * 256 + tid;
        int n   = lin >> 4;
        int c8  = (lin & 15) * 8;
        *(uint4*)&Bt[n * 136 + c8] = *(const uint4*)&tokens[(size_t)(nt0 + n) * CH + c8];
    }
    wd_l[tid]       = wd[(size_t)nt0 * 4 + tid];
    wd_l[256 + tid] = wd[(size_t)nt0 * 4 + 256 + tid];
    #pragma unroll
    for (int r = 0; r < 2; r++) {
        int idx = r * 256 + tid;
        float iv = ebn_g[idx] / sqrtf(ebn_v[idx] + BNE);
        inv_l[idx] = iv;
        sh_l[idx]  = ebn_b[idx] - ebn_m[idx] * iv;
    }

    f32x4 oacc[4][4];
    #pragma unroll
    for (int i = 0; i < 4; i++)
        #pragma unroll
        for (int j = 0; j < 4; j++) oacc[i][j] = zero4();

    for (int e = 0; e < NEXP; e++) {
        __syncthreads();
        #pragma unroll
        for (int rep = 0; rep < 8; rep++) {
            int lin = rep * 256 + tid;
            int o   = lin >> 4;
            int c8  = (lin & 15) * 8;
            *(uint4*)&Ac[o * 136 + c8] = *(const uint4*)&cen[(size_t)e * CH * CH + o * CH + c8];
        }
        __syncthreads();

        f32x4 acc[4][4];
        #pragma unroll
        for (int i = 0; i < 4; i++)
            #pragma unroll
            for (int j = 0; j < 4; j++) acc[i][j] = zero4();

        #pragma unroll
        for (int kk = 0; kk < 4; kk++) {
            int ko = kk * 32 + quad * 8;
            s16x8 a[4], bb[4];
            #pragma unroll
            for (int i = 0; i < 4; i++) {
                a[i]  = *(const s16x8*)&Ac[(qm * 64 + i * 16 + n15) * 136 + ko];
                bb[i] = *(const s16x8*)&Bt[(qn * 64 + i * 16 + n15) * 136 + ko];
            }
            #pragma unroll
            for (int mt = 0; mt < 4; mt++)
                #pragma unroll
                for (int nt = 0; nt < 4; nt++)
                    acc[mt][nt] = __builtin_amdgcn_mfma_f32_16x16x32_bf16(a[mt], bb[nt], acc[mt][nt], 0, 0, 0);
        }

        #pragma unroll
        for (int mt = 0; mt < 4; mt++)
            #pragma unroll
            for (int nt = 0; nt < 4; nt++) {
                float wde = wd_l[(qn * 64 + nt * 16 + n15) * 4 + e];
                #pragma unroll
                for (int r = 0; r < 4; r++) {
                    int o = qm * 64 + mt * 16 + quad * 4 + r;
                    float y = acc[mt][nt][r] * inv_l[e * CH + o] + sh_l[e * CH + o];
                    oacc[mt][nt][r] += wde * (y / (1.0f + __expf(-y)));
                }
            }
    }

    // coalesced epilogue: oacc -> Bt (LDS scatter, conflict-free pitch 136) -> uint4 row stores
    __syncthreads();   // last expert's MFMA reads of Bt done
    #pragma unroll
    for (int mt = 0; mt < 4; mt++)
        #pragma unroll
        for (int nt = 0; nt < 4; nt++) {
            int tk = qn * 64 + nt * 16 + n15;
            int ob = qm * 64 + mt * 16 + quad * 4;
            ushort4 pk;
            pk.x = f2bf(oacc[mt][nt][0]); pk.y = f2bf(oacc[mt][nt][1]);
            pk.z = f2bf(oacc[mt][nt][2]); pk.w = f2bf(oacc[mt][nt][3]);
            *(ushort4*)&Bt[tk * 136 + ob] = pk;
        }
    __syncthreads();
    #pragma unroll
    for (int rep = 0; rep < 8; rep++) {
        int lin = rep * 256 + tid;
        int n   = lin >> 4;
        int c8  = (lin & 15) * 8;
        *(uint4*)&moe[(size_t)(nt0 + n) * CH + c8] = *(const uint4*)&Bt[n * 136 + c8];
    }
}

// ---------------------------------------------------------------- k3: conv3 + BN + SiLU + residual
// (frozen from R4) grid 3200 x 64 tokens. B-tile staged once; w3p global->VGPR per slice;
// coalesced epilogue via LDS f32 transpose.
__global__ __launch_bounds__(256, 3) void k3_conv3(
    const unsigned short* __restrict__ moe, const unsigned short* __restrict__ w3p,
    const float* __restrict__ bn3_g, const float* __restrict__ bn3_b,
    const float* __restrict__ bn3_m, const float* __restrict__ bn3_v,
    const float* __restrict__ x, float* __restrict__ out)
{
    const int tid  = threadIdx.x;
    const int lane = tid & 63;
    const int wv   = tid >> 6;
    const int n15  = lane & 15;
    const int quad = lane >> 4;
    const int nt0  = blockIdx.x * 64;
    const int b    = nt0 / HWSZ;
    const int hw0  = nt0 % HWSZ;

    __shared__ union {
        unsigned short B3[64 * 136];   // moe tile [tok][c] pitch 136 (17.4 KB)
        float scr[128 * 68];           // f32 transpose scratch [o_l][tok] pitch 68 (34.8 KB)
    } u;
    __shared__ float s3_l[256], t3_l[256];

    {
        float s = bn3_g[tid] / sqrtf(bn3_v[tid] + BNE);
        s3_l[tid] = s;
        t3_l[tid] = bn3_b[tid] - bn3_m[tid] * s;
    }

    #pragma unroll
    for (int rep = 0; rep < 2; rep++) {
        int lin = rep * 256 + tid;
        int n   = lin >> 3;
        int c16 = (lin & 7) * 16;
        *(uint4*)&u.B3[n * 136 + c16]     = *(const uint4*)&moe[(size_t)(nt0 + n) * CH + c16];
        *(uint4*)&u.B3[n * 136 + c16 + 8] = *(const uint4*)&moe[(size_t)(nt0 + n) * CH + c16 + 8];
    }

    f32x4 acc[4][4];
    #pragma unroll
    for (int i = 0; i < 4; i++)
        #pragma unroll
        for (int j = 0; j < 4; j++) acc[i][j] = zero4();

    __syncthreads();

    for (int s = 0; s < 4; s++) {
        s16x8 af[4];
        #pragma unroll
        for (int mt = 0; mt < 4; mt++) {
            int row = (wv * 4 + mt) * 16 + n15;
            af[mt] = *(const s16x8*)&w3p[(s * 256 + row) * 32 + quad * 8];
        }
        s16x8 bf[4];
        #pragma unroll
        for (int nt = 0; nt < 4; nt++)
            bf[nt] = *(const s16x8*)&u.B3[(nt * 16 + n15) * 136 + s * 32 + quad * 8];
        #pragma unroll
        for (int mt = 0; mt < 4; mt++)
            #pragma unroll
            for (int nt = 0; nt < 4; nt++)
                acc[mt][nt] = __builtin_amdgcn_mfma_f32_16x16x32_bf16(af[mt], bf[nt], acc[mt][nt], 0, 0, 0);
    }

    #pragma unroll
    for (int h = 0; h < 2; h++) {
        __syncthreads();
        if ((wv >> 1) == h) {
            int wvl = wv & 1;
            #pragma unroll
            for (int mt = 0; mt < 4; mt++)
                #pragma unroll
                for (int nt = 0; nt < 4; nt++) {
                    int tk = nt * 16 + n15;
                    #pragma unroll
                    for (int r = 0; r < 4; r++) {
                        int o_l = wvl * 64 + mt * 16 + quad * 4 + r;
                        int o2  = h * 128 + o_l;
                        float y = acc[mt][nt][r] * s3_l[o2] + t3_l[o2];
                        u.scr[o_l * 68 + tk] = y / (1.0f + __expf(-y));
                    }
                }
        }
        __syncthreads();
        #pragma unroll
        for (int rep = 0; rep < 8; rep++) {
            int lin = rep * 256 + tid;
            int row = lin >> 4;
            int t4  = (lin & 15) * 4;
            int o2  = h * 128 + row;
            size_t g = ((size_t)(b * C2 + o2)) * HWSZ + hw0 + t4;
            f32x4 v = *(const f32x4*)&u.scr[row * 68 + t4];
            const float4 xs = *(const float4*)&x[g];
            float4 w;
            w.x = v[0] + xs.x; w.y = v[1] + xs.y; w.z = v[2] + xs.z; w.w = v[3] + xs.w;
            *(float4*)&out[g] = w;
        }
    }
}

// ----------------------------------------------------------------
extern "C" void kernel_launch(void* const* d_in, const int* in_sizes, int n_in,
                              void* d_out, int out_size, void* d_ws, size_t ws_size,
                              hipStream_t stream) {
    const float* x     = (const float*)d_in[0];
    const float* w1    = (const float*)d_in[1];
    const float* bn1_g = (const float*)d_in[2];
    const float* bn1_b = (const float*)d_in[3];
    const float* bn1_m = (const float*)d_in[4];
    const float* bn1_v = (const float*)d_in[5];
    const float* rw    = (const float*)d_in[6];
    const float* rb    = (const float*)d_in[7];
    const float* ew    = (const float*)d_in[8];
    const float* ebn_g = (const float*)d_in[9];
    const float* ebn_b = (const float*)d_in[10];
    const float* ebn_m = (const float*)d_in[11];
    const float* ebn_v = (const float*)d_in[12];
    const float* w3    = (const float*)d_in[13];
    const float* bn3_g = (const float*)d_in[14];
    const float* bn3_b = (const float*)d_in[15];
    const float* bn3_m = (const float*)d_in[16];
    const float* bn3_v = (const float*)d_in[17];
    float* out = (float*)d_out;

    char* ws = (char*)d_ws;
    unsigned short* tokens = (unsigned short*)(ws);                // N*128 bf16
    unsigned short* moe    = (unsigned short*)(ws + 52428800);     // N*128 bf16
    float*          wdv    = (float*)(ws + 104857600);             // N*4 f32
    unsigned short* cen    = (unsigned short*)(ws + 108134400);    // 4*128*128 bf16 = 131072 B
    _Float16*       w1s    = (_Float16*)(ws + 108265472);          // 2*128*256 f16 = 131072 B
    unsigned short* w3p    = (unsigned short*)(ws + 108396544);    // 256*128 bf16 = 65536 B

    k0_pack<<<dim3(512), dim3(256), 0, stream>>>(ew, w1, w3, cen, w1s, w3p);
    k1_conv1_router<<<dim3(3200), dim3(256), 0, stream>>>(x, w1s, bn1_g, bn1_b, bn1_m, bn1_v,
                                                          rw, rb, tokens, wdv);
    k2_experts<<<dim3(1600), dim3(256), 0, stream>>>(tokens, cen, wdv,
                                                     ebn_g, ebn_b, ebn_m, ebn_v, moe);
    k3_conv3<<<dim3(3200), dim3(256), 0, stream>>>(moe, w3p, bn3_g, bn3_b, bn3_m, bn3_v, x, out);
    (void)in_sizes; (void)n_in; (void)out_size; (void)ws_size;
}